// Round 7
// baseline (203.984 us; speedup 1.0000x reference)
//
#include <hip/hip_runtime.h>
#include <math.h>

#define NB 16
#define NA 16384
#define NC 81
#define TOPK 50
#define NBK 255                            // u8 buckets 0..254 (255=sentinel)
#define TRC 1024                           // lazy tranche capacity (R3-verified best)
#define NEGF (-__builtin_inff())
#define SUPC 0.5000000298023223876953125   // 0.5 + 2^-25 (exact in double)

typedef unsigned long long ull;

// ws layout: boxes [NB*NA*4 f32] @0 (4 MiB), confT8 [NB*NC*NA u8] @4 MiB (21.2 MB)
#define WS_CONFT_OFF  ((size_t)4194304)
#define WS_FULL  (WS_CONFT_OFF + (size_t)NB * NC * NA)       // 25,427,968

// exact f32 form of: round_f32(inter/den) > 0.5  (== inter > den*(0.5+2^-25))
__device__ __forceinline__ bool iou_gt_half(float inter, float den) {
    return fmaf(den, -0.5f, inter) > den * 0x1p-25f;
}

// score -> u8 code: 8-bit DESCENDING bucket for v in (0.5,1); 0xFF = not-candidate.
__device__ __forceinline__ unsigned enc8(float v) {
    unsigned e = 0xFFu;
    if (v > 0.5f) {
        unsigned d = 255u - ((__float_as_uint(v) >> 15) & 0xFFu);
        e = (d > 254u) ? 254u : d;
    }
    return e;
}

// ---------------- decode + clip (bit-verified rounds 1-8 — DO NOT TOUCH) ----------
__device__ __forceinline__ void decode_body(int i, const float* __restrict__ loc,
                                            const float* __restrict__ anc,
                                            float* __restrict__ boxes) {
#pragma clang fp contract(off)
    int a = i & (NA - 1);
    float4 an = ((const float4*)anc)[a];
    float4 ld = ((const float4*)loc)[i];
    float cx = an.x + (ld.x * 0.1f) * an.z;
    float cy = an.y + (ld.y * 0.1f) * an.w;
    float w = an.z * (float)exp((double)(ld.z * 0.2f));
    float h = an.w * (float)exp((double)(ld.w * 0.2f));
    float x1 = cx - w * 0.5f;
    float y1 = cy - h * 0.5f;
    float x2 = x1 + w;
    float y2 = y1 + h;
    x1 = fminf(fmaxf(x1, 0.f), 1.f);
    y1 = fminf(fmaxf(y1, 0.f), 1.f);
    x2 = fminf(fmaxf(x2, 0.f), 1.f);
    y2 = fminf(fmaxf(y2, 0.f), 1.f);
    ((float4*)boxes)[i] = make_float4(x1, y1, x2, y2);
}

__global__ __launch_bounds__(256) void decode_k(const float* __restrict__ loc,
                                                const float* __restrict__ anc,
                                                float* __restrict__ boxes) {
    int i = blockIdx.x * 256 + threadIdx.x;
    if (i < NB * NA) decode_body(i, loc, anc, boxes);
}

// ------- fused prep: decode (1 box/thread) + u8-code transpose slab (1:1 mapping) ----
#define TSLAB 256
__global__ __launch_bounds__(256) void prep_k(const float* __restrict__ conf,
                                              const float* __restrict__ loc,
                                              const float* __restrict__ anc,
                                              float* __restrict__ boxes,
                                              unsigned char* __restrict__ confT) {
    __shared__ unsigned char code[TSLAB * NC];     // 20736 B
    const int t = threadIdx.x;
    const int b = blockIdx.y, slab = blockIdx.x;
    // --- decode: thread t owns box (b, slab*256+t) — exp latency hides under loads ---
    decode_body(b * NA + slab * TSLAB + t, loc, anc, boxes);
    // --- transpose: conf f32 [B,A,C] -> confT8 u8 codes [B,C,A] ---
    const float4* src = (const float4*)(conf + ((size_t)b * NA + (size_t)slab * TSLAB) * NC);
    for (int i = t; i < (TSLAB * NC) / 4; i += 256) {
        float4 v = src[i];
        unsigned wrd = enc8(v.x) | (enc8(v.y) << 8) | (enc8(v.z) << 16) | (enc8(v.w) << 24);
        *(unsigned*)&code[4 * i] = wrd;            // contiguous 4 B/lane: conflict-free
    }
    __syncthreads();
    const int lane = t & 63, wv = t >> 6;
    for (int c = wv; c < NC; c += 4) {             // 64 lanes x 4 B = 256 B run per class
        unsigned v = 0u;
#pragma unroll
        for (int j = 0; j < 4; ++j)
            v |= (unsigned)code[(4 * lane + j) * NC + c] << (8 * j);
        *(unsigned*)(confT + ((size_t)b * NC + c) * NA + (size_t)slab * TSLAB + 4 * lane) = v;
    }
}

// ---- histogram/scatter over a 16-code word-quad (static indices; Q dies in-iter) ----
#define HIST16W(Q)                                                         \
    do {                                                                   \
        unsigned wrds_[4] = {(Q).x, (Q).y, (Q).z, (Q).w};                  \
        _Pragma("unroll")                                                  \
        for (int m_ = 0; m_ < 4; ++m_) {                                   \
            _Pragma("unroll")                                              \
            for (int k_ = 0; k_ < 4; ++k_) {                               \
                unsigned bk_ = (wrds_[m_] >> (8 * k_)) & 0xFFu;            \
                if (bk_ != 0xFFu) atomicAdd(&s_cnt[bk_], 1u);              \
            }                                                              \
        }                                                                  \
    } while (0)

#define SCAT16W(Q, BA)                                                     \
    do {                                                                   \
        unsigned wrds_[4] = {(Q).x, (Q).y, (Q).z, (Q).w};                  \
        _Pragma("unroll")                                                  \
        for (int m_ = 0; m_ < 4; ++m_) {                                   \
            _Pragma("unroll")                                              \
            for (int k_ = 0; k_ < 4; ++k_) {                               \
                int bk_ = (int)((wrds_[m_] >> (8 * k_)) & 0xFFu);          \
                if (bk_ >= trLo && bk_ < trHi)                             \
                    s_ix[atomicAdd(&s_cur[bk_], 1u)] =                     \
                        (unsigned short)((BA) + 4 * m_ + k_);              \
            }                                                              \
        }                                                                  \
    } while (0)

// ---- wave-per-class greedy NMS v13: no inter-wave barriers, in-wave resolve --------
// One 64-lane wave owns one (batch,class). All control state (nacc, chunk bounds,
// prefetch) lives in registers in lockstep; accepted boxes relay via shfl + tiny LDS.
__global__ __launch_bounds__(64, 4) void nmsW_k(const unsigned char* __restrict__ confT,
                                                const float* __restrict__ conf,
                                                const float* __restrict__ boxes,
                                                float* __restrict__ out) {
#pragma clang fp contract(off)
    const int blk = blockIdx.x;
    const int b = blk / NC, c = blk - b * NC;
    const int lane = threadIdx.x;                  // 0..63, exactly one wave

    __shared__ unsigned short s_ix[TRC];           // 2048 B
    __shared__ unsigned s_off[NBK + 1];            // 1024 B bucket starts
    __shared__ unsigned s_cnt[NBK + 1];            // 1024 B hist bins
    __shared__ unsigned s_cur[NBK];                // 1020 B scatter cursors
    __shared__ float4 s_abox[TOPK];                // 800 B accepted boxes
    __shared__ float s_aarea[TOPK];                // 200 B accepted areas
    __shared__ int s_m;                            // slow-path counter

    const uint4* row16 = (const uint4*)(confT + ((size_t)b * NC + c) * NA); // 16 codes/16B
    const float* cp = conf + ((size_t)b * NA) * NC + c;   // exact scores, L3-hot
    const float4* bb = (const float4*)boxes + (size_t)b * NA;
    float* orow = out + ((size_t)b * NC + c) * (TOPK * 5);

#pragma unroll
    for (int k = 0; k < 4; ++k) s_cnt[4 * lane + k] = 0u;
    __syncthreads();

    // --- histogram: 16 uint4/lane, codes die in-iteration (no spill) ---
    for (int r = 0; r < 16; ++r) {
        uint4 q = row16[lane + 64 * r];
        HIST16W(q);
    }
    __syncthreads();

    // --- maxbucket + exclusive prefix: lane l owns bins [4l, 4l+4) ---
    unsigned c4[4]; unsigned tot = 0u, maxb = 0u;
#pragma unroll
    for (int k = 0; k < 4; ++k) {
        int idx = 4 * lane + k;
        c4[k] = (idx < NBK) ? s_cnt[idx] : 0u;
        tot += c4[k];
        maxb = (c4[k] > maxb) ? c4[k] : maxb;
    }
#pragma unroll
    for (int off = 32; off; off >>= 1) {
        unsigned o = __shfl_xor(maxb, off);
        maxb = (o > maxb) ? o : maxb;
    }
    unsigned incl = tot;
#pragma unroll
    for (int off = 1; off < 64; off <<= 1) {
        unsigned o = __shfl_up(incl, off);
        if (lane >= off) incl += o;
    }
    unsigned e = incl - tot;
#pragma unroll
    for (int k = 0; k < 4; ++k) {
        int idx = 4 * lane + k;
        if (idx < NBK) s_off[idx] = e;
        e += c4[k];
    }
    if (lane == 63) s_off[NBK] = e;
    __syncthreads();

    int nacc = 0;

    if (maxb <= (unsigned)TRC) {
        // =========================== fast path: tranche loop ===========================
        int trLo = 0;
        while (true) {
            int trHi = trLo;
            while (trHi < NBK && s_off[trHi + 1] - s_off[trLo] <= (unsigned)TRC) trHi++;
            const unsigned tbase = s_off[trLo], tend = s_off[trHi];
            if (tbase == tend) break;              // no candidates remain
            const int tlen = (int)(tend - tbase);
            for (int i = trLo + lane; i < trHi; i += 64) s_cur[i] = s_off[i] - tbase;
            __syncthreads();
            // --- scatter tranche's anchor indices (code row is L2/L3-hot, 16 KB) ---
            for (int r = 0; r < 16; ++r) {
                uint4 q = row16[lane + 64 * r];
                SCAT16W(q, 16 * (lane + 64 * r));
            }
            __syncthreads();

            int bptr = trLo;
            int pf_pos = -1;                       // next-window prefetch (same tranche only)
            float4 pf_box = make_float4(0.f, 0.f, 0.f, 0.f);

            // --- rounds: one <=64-candidate bucket-aligned window, test + in-wave resolve ---
            while (nacc < TOPK) {
                if (bptr >= trHi || (int)(s_off[bptr] - tbase) >= tlen) break;
                const int e0 = (int)(s_off[bptr] - tbase);
                int bpl = bptr;
                while (bpl < trHi && (int)(s_off[bpl + 1] - tbase) - e0 <= 64) bpl++;
                int e1 = (bpl < trHi) ? (int)(s_off[bpl] - tbase) : tlen;
                int mode = 0;
                if (e1 == e0) {                    // first bucket > 64 entries (rare)
                    mode = 1;
                    e1 = (int)(s_off[bptr + 1] - tbase);
                    bptr = bptr + 1;
                } else {
                    bptr = bpl;
                }

                if (mode == 0) {
                    const int mc = e1 - e0;
                    const bool valid = lane < mc;
                    int ii = e0 + lane; if (ii > TRC - 1) ii = TRC - 1;
                    int a = valid ? (int)s_ix[ii] : 0;
                    float4 bxv = (pf_pos == e0) ? pf_box : bb[a];
                    float myscore = valid ? cp[(size_t)a * NC] : 0.f;
                    if (!valid) bxv = make_float4(0.f, 0.f, 0.f, 0.f);
                    float mar = (bxv.z - bxv.x) * (bxv.w - bxv.y);
                    // issue next-window loads now; they retire under the test loop
                    {
                        int pi = e1 + lane; if (pi > TRC - 1) pi = TRC - 1;
                        int pa = (e1 + lane < tlen) ? (int)s_ix[pi] : 0;
                        pf_box = bb[pa];
                        pf_pos = e1;
                    }
                    bool kill = !valid;
                    for (int j = 0; j < nacc; ++j) {
                        float4 ab = s_abox[j];
                        float aa = s_aarea[j];
                        float xx1 = fmaxf(ab.x, bxv.x), yy1 = fmaxf(ab.y, bxv.y);
                        float xx2 = fminf(ab.z, bxv.z), yy2 = fminf(ab.w, bxv.w);
                        float iw = fmaxf(xx2 - xx1, 0.f), ih = fmaxf(yy2 - yy1, 0.f);
                        float inter = iw * ih;
                        float den = (aa + mar) - inter;
                        if (iou_gt_half(inter, den)) kill = true;
                    }
                    unsigned long long alive = ~__ballot(kill);
                    if (mc < 64) alive &= (1ull << mc) - 1ull;
                    unsigned long long mykey =
                        ((unsigned long long)__float_as_uint(myscore) << 32) |
                        (unsigned)(16383 - a);
                    while (alive && nacc < TOPK) {
                        unsigned long long kk = ((alive >> lane) & 1ull) ? mykey : 0ull;
                        int src = lane;
#pragma unroll
                        for (int off = 32; off; off >>= 1) {
                            unsigned long long ok = __shfl_xor(kk, off);
                            int osrc = __shfl_xor(src, off);
                            if (ok > kk) { kk = ok; src = osrc; }
                        }
                        float wx = __shfl(bxv.x, src), wy = __shfl(bxv.y, src);
                        float wz = __shfl(bxv.z, src), ww = __shfl(bxv.w, src);
                        float wscore = __shfl(myscore, src);
                        float war = (wz - wx) * (ww - wy);
                        if (lane == 0) {
                            orow[nacc * 5 + 0] = wscore;
                            orow[nacc * 5 + 1] = wx; orow[nacc * 5 + 2] = wy;
                            orow[nacc * 5 + 3] = wz; orow[nacc * 5 + 4] = ww;
                            s_abox[nacc] = make_float4(wx, wy, wz, ww);
                            s_aarea[nacc] = war;
                        }
                        nacc++;
                        alive &= ~(1ull << src);
                        if (alive) {
                            float xx1 = fmaxf(wx, bxv.x), yy1 = fmaxf(wy, bxv.y);
                            float xx2 = fminf(wz, bxv.z), yy2 = fminf(ww, bxv.w);
                            float iw = fmaxf(xx2 - xx1, 0.f), ih = fmaxf(yy2 - yy1, 0.f);
                            float inter = iw * ih;
                            float den = (war + mar) - inter;
                            bool sup = iou_gt_half(inter, den);
                            alive &= ~__ballot(sup);
                        }
                    }
                    __syncthreads();               // s_abox writes -> next round's test
                } else {
                    // big-bucket (>64 in one bucket, <=TRC): strided extraction
                    pf_pos = -1;
                    while (nacc < TOPK) {
                        unsigned long long bk = 0ull; int bpos = 0;
                        for (int i = e0 + lane; i < e1; i += 64) {
                            int av = (int)s_ix[i];
                            if (av != 0xFFFF) {
                                float vv = cp[(size_t)av * NC];
                                unsigned long long k =
                                    ((unsigned long long)__float_as_uint(vv) << 32) |
                                    (unsigned)(16383 - av);
                                if (k > bk) { bk = k; bpos = i; }
                            }
                        }
#pragma unroll
                        for (int off = 32; off; off >>= 1) {
                            unsigned long long ok = __shfl_xor(bk, off);
                            int op = __shfl_xor(bpos, off);
                            if (ok > bk) { bk = ok; bpos = op; }
                        }
                        if (bk == 0ull) break;
                        int a = (int)s_ix[bpos];
                        float wscore = __uint_as_float((unsigned)(bk >> 32));
                        if (lane == 0) s_ix[bpos] = 0xFFFFu;     // consume
                        float4 wb = bb[a];
                        float war = (wb.z - wb.x) * (wb.w - wb.y);
                        bool sup = false;
                        if (lane < nacc) {
                            float4 ab = s_abox[lane];
                            float aa = s_aarea[lane];
                            float xx1 = fmaxf(ab.x, wb.x), yy1 = fmaxf(ab.y, wb.y);
                            float xx2 = fminf(ab.z, wb.z), yy2 = fminf(ab.w, wb.w);
                            float iw = fmaxf(xx2 - xx1, 0.f), ih = fmaxf(yy2 - yy1, 0.f);
                            float inter = iw * ih;
                            float den = (aa + war) - inter;
                            sup = iou_gt_half(inter, den);
                        }
                        if (__ballot(sup) == 0ull) {
                            if (lane == 0) {
                                orow[nacc * 5 + 0] = wscore;
                                orow[nacc * 5 + 1] = wb.x; orow[nacc * 5 + 2] = wb.y;
                                orow[nacc * 5 + 3] = wb.z; orow[nacc * 5 + 4] = wb.w;
                                s_abox[nacc] = wb;
                                s_aarea[nacc] = war;
                            }
                            nacc++;
                        }
                    }
                    __syncthreads();
                }
            }
            // --- tranche done ---
            if (nacc >= TOPK || trHi >= NBK) break;
            trLo = trHi;
            __syncthreads();
        }
    } else {
        // ===== exact windowed path (single bucket > TRC; P~0): strided conf scan =====
        float hi = 1.0f, delta = 0.02f;
        while (true) {
            if (nacc >= TOPK || hi <= 0.5f) break;
            float lo = fmaxf(hi - delta, 0.5f);
            if (lane == 0) s_m = 0;
            __syncthreads();
            for (int a = lane; a < NA; a += 64) {
                float vv = cp[(size_t)a * NC];
                if (vv > lo && vv <= hi) {
                    int p = atomicAdd(&s_m, 1);
                    if (p < TRC) s_ix[p] = (unsigned short)a;
                }
            }
            __syncthreads();
            int m = s_m;
            if (m > TRC) { delta *= 0.5f; continue; }
            while (nacc < TOPK) {
                unsigned long long bk = 0ull; int bpos = 0;
                for (int i = lane; i < m; i += 64) {
                    int av = (int)s_ix[i];
                    if (av != 0xFFFF) {
                        float vv = cp[(size_t)av * NC];
                        unsigned long long k =
                            ((unsigned long long)__float_as_uint(vv) << 32) |
                            (unsigned)(16383 - av);
                        if (k > bk) { bk = k; bpos = i; }
                    }
                }
#pragma unroll
                for (int off = 32; off; off >>= 1) {
                    unsigned long long ok = __shfl_xor(bk, off);
                    int op = __shfl_xor(bpos, off);
                    if (ok > bk) { bk = ok; bpos = op; }
                }
                if (bk == 0ull) break;
                int a = (int)s_ix[bpos];
                float wscore = __uint_as_float((unsigned)(bk >> 32));
                if (lane == 0) s_ix[bpos] = 0xFFFFu;
                float4 wb = bb[a];
                float war = (wb.z - wb.x) * (wb.w - wb.y);
                bool sup = false;
                if (lane < nacc) {
                    float4 ab = s_abox[lane];
                    float aa = s_aarea[lane];
                    float xx1 = fmaxf(ab.x, wb.x), yy1 = fmaxf(ab.y, wb.y);
                    float xx2 = fminf(ab.z, wb.z), yy2 = fminf(ab.w, wb.w);
                    float iw = fmaxf(xx2 - xx1, 0.f), ih = fmaxf(yy2 - yy1, 0.f);
                    float inter = iw * ih;
                    float den = (aa + war) - inter;
                    sup = iou_gt_half(inter, den);
                }
                if (__ballot(sup) == 0ull) {
                    if (lane == 0) {
                        orow[nacc * 5 + 0] = wscore;
                        orow[nacc * 5 + 1] = wb.x; orow[nacc * 5 + 2] = wb.y;
                        orow[nacc * 5 + 3] = wb.z; orow[nacc * 5 + 4] = wb.w;
                        s_abox[nacc] = wb;
                        s_aarea[nacc] = war;
                    }
                    nacc++;
                }
            }
            __syncthreads();
            hi = lo;
        }
    }

    for (int z = nacc * 5 + lane; z < TOPK * 5; z += 64) orow[z] = 0.f;
}

// ============== round-1 fallback (only if ws too small for fast path) ==============
#define OTHREADS 1024
#define OCAP 10240
#define OJMAX 10

__global__ __launch_bounds__(OTHREADS) void nms_old_k(const float* __restrict__ conf,
                                                      const float* __restrict__ boxes,
                                                      float* __restrict__ out) {
#pragma clang fp contract(off)
    const int blk = blockIdx.x;
    const int b = blk / NC, c = blk - b * NC;
    const int t = threadIdx.x;
    const int lane = t & 63, wid = t >> 6;
    __shared__ float s_val[OCAP];
    __shared__ unsigned short s_idx[OCAP];
    __shared__ float s_ps[2][16];
    __shared__ int s_pa[2][16];
    __shared__ int s_n;
    if (t == 0) s_n = 0;
    __syncthreads();
    const float* cp = conf + ((size_t)b * NA) * NC + c;
    float v[NA / OTHREADS];
#pragma unroll
    for (int r = 0; r < NA / OTHREADS; ++r)
        v[r] = cp[(size_t)(r * OTHREADS + t) * NC];
#pragma unroll
    for (int r = 0; r < NA / OTHREADS; ++r) {
        int a = r * OTHREADS + t;
        bool alive = v[r] > 0.5f;
        unsigned long long m = __ballot(alive);
        int cnt = __popcll(m);
        int base = 0;
        if (lane == 0 && cnt) base = atomicAdd(&s_n, cnt);
        base = __shfl(base, 0);
        if (alive) {
            int p = base + __popcll(m & ((1ull << lane) - 1));
            if (p < OCAP) { s_val[p] = v[r]; s_idx[p] = (unsigned short)a; }
        }
    }
    __syncthreads();
    int n = s_n; if (n > OCAP) n = OCAP;
    const int jn = (n + OTHREADS - 1) / OTHREADS;
    const float4* bb = (const float4*)boxes + (size_t)b * NA;
    float sc[OJMAX]; float4 bx[OJMAX]; int ia[OJMAX];
#pragma unroll
    for (int j = 0; j < OJMAX; ++j) {
        sc[j] = NEGF; ia[j] = 0x7fffffff; bx[j] = make_float4(0.f, 0.f, 0.f, 0.f);
        int p = j * OTHREADS + t;
        if (p < n) { sc[j] = s_val[p]; ia[j] = (int)s_idx[p]; bx[j] = bb[ia[j]]; }
    }
    float* orow = out + (size_t)blk * (TOPK * 5);
    int k = 0;
    for (; k < TOPK; ++k) {
        float ms = NEGF; int ma = 0x7fffffff;
#pragma unroll
        for (int j = 0; j < OJMAX; ++j) {
            if (j < jn) {
                bool better = (sc[j] > ms) || (sc[j] == ms && ia[j] < ma);
                ms = better ? sc[j] : ms;
                ma = better ? ia[j] : ma;
            }
        }
#pragma unroll
        for (int off = 32; off; off >>= 1) {
            float os = __shfl_xor(ms, off);
            int oa = __shfl_xor(ma, off);
            if (os > ms || (os == ms && oa < ma)) { ms = os; ma = oa; }
        }
        int pb = k & 1;
        if (lane == 0) { s_ps[pb][wid] = ms; s_pa[pb][wid] = ma; }
        __syncthreads();
        float wsv = NEGF; int wa = 0x7fffffff;
#pragma unroll
        for (int w = 0; w < 16; ++w) {
            float os = s_ps[pb][w]; int oa = s_pa[pb][w];
            if (os > wsv || (os == wsv && oa < wa)) { wsv = os; wa = oa; }
        }
        if (!(wsv > NEGF)) break;
        float4 wb = bb[wa];
        float warea = (wb.z - wb.x) * (wb.w - wb.y);
        if (t == 0) {
            orow[k * 5 + 0] = wsv;
            orow[k * 5 + 1] = wb.x; orow[k * 5 + 2] = wb.y;
            orow[k * 5 + 3] = wb.z; orow[k * 5 + 4] = wb.w;
        }
#pragma unroll
        for (int j = 0; j < OJMAX; ++j) {
            if (j < jn) {
                float xx1 = fmaxf(wb.x, bx[j].x);
                float yy1 = fmaxf(wb.y, bx[j].y);
                float xx2 = fminf(wb.z, bx[j].z);
                float yy2 = fminf(wb.w, bx[j].w);
                float iw = fmaxf(xx2 - xx1, 0.f);
                float ih = fmaxf(yy2 - yy1, 0.f);
                float inter = iw * ih;
                float aj = (bx[j].z - bx[j].x) * (bx[j].w - bx[j].y);
                float denom = (warea + aj) - inter;
                bool supp = ((double)inter > (double)denom * SUPC) || (ia[j] == wa);
                if (supp) sc[j] = NEGF;
            }
        }
    }
    for (int z = k * 5 + t; z < TOPK * 5; z += OTHREADS) orow[z] = 0.f;
}

extern "C" void kernel_launch(void* const* d_in, const int* in_sizes, int n_in,
                              void* d_out, int out_size, void* d_ws, size_t ws_size,
                              hipStream_t stream) {
    const float* conf = (const float*)d_in[0];   // [B,A,C] f32
    const float* loc  = (const float*)d_in[1];   // [B,A,4] f32
    const float* anc  = (const float*)d_in[2];   // [A,4]   f32
    float* boxes = (float*)d_ws;

    if (ws_size >= WS_FULL) {
        unsigned char* confT = (unsigned char*)((char*)d_ws + WS_CONFT_OFF);
        dim3 tg(NA / TSLAB, NB);                 // fused decode+transpose, 1024 blocks
        prep_k<<<tg, 256, 0, stream>>>(conf, loc, anc, boxes, confT);
        nmsW_k<<<NB * NC, 64, 0, stream>>>(confT, conf, boxes, (float*)d_out);
    } else {
        decode_k<<<(NB * NA + 255) / 256, 256, 0, stream>>>(loc, anc, boxes);
        nms_old_k<<<NB * NC, OTHREADS, 0, stream>>>(conf, boxes, (float*)d_out);
    }
}

// Round 8
// 196.502 us; speedup vs baseline: 1.0381x; 1.0381x over previous
//
#include <hip/hip_runtime.h>
#include <math.h>

#define NB 16
#define NA 16384
#define NC 81
#define TOPK 50
#define NBK 255                            // u8 buckets 0..254 (255=sentinel)
#define TRC 1024                           // lazy tranche capacity (R3-verified best)
#define NEGF (-__builtin_inff())
#define SUPC 0.5000000298023223876953125   // 0.5 + 2^-25 (exact in double)

typedef unsigned long long ull;

// ws layout: boxes [NB*NA*4 f32] @0 (4 MiB), confT8 [NB*NC*NA u8] @4 MiB (21.2 MB)
#define WS_CONFT_OFF  ((size_t)4194304)
#define WS_FULL  (WS_CONFT_OFF + (size_t)NB * NC * NA)       // 25,427,968

// exact f32 form of: round_f32(inter/den) > 0.5  (== inter > den*(0.5+2^-25))
__device__ __forceinline__ bool iou_gt_half(float inter, float den) {
    return fmaf(den, -0.5f, inter) > den * 0x1p-25f;
}

// score -> u8 code: 8-bit DESCENDING bucket for v in (0.5,1); 0xFF = not-candidate.
__device__ __forceinline__ unsigned enc8(float v) {
    unsigned e = 0xFFu;
    if (v > 0.5f) {
        unsigned d = 255u - ((__float_as_uint(v) >> 15) & 0xFFu);
        e = (d > 254u) ? 254u : d;
    }
    return e;
}

// ---------------- decode + clip (bit-verified rounds 1-8 — DO NOT TOUCH) ----------
__device__ __forceinline__ void decode_body(int i, const float* __restrict__ loc,
                                            const float* __restrict__ anc,
                                            float* __restrict__ boxes) {
#pragma clang fp contract(off)
    int a = i & (NA - 1);
    float4 an = ((const float4*)anc)[a];
    float4 ld = ((const float4*)loc)[i];
    float cx = an.x + (ld.x * 0.1f) * an.z;
    float cy = an.y + (ld.y * 0.1f) * an.w;
    float w = an.z * (float)exp((double)(ld.z * 0.2f));
    float h = an.w * (float)exp((double)(ld.w * 0.2f));
    float x1 = cx - w * 0.5f;
    float y1 = cy - h * 0.5f;
    float x2 = x1 + w;
    float y2 = y1 + h;
    x1 = fminf(fmaxf(x1, 0.f), 1.f);
    y1 = fminf(fmaxf(y1, 0.f), 1.f);
    x2 = fminf(fmaxf(x2, 0.f), 1.f);
    y2 = fminf(fmaxf(y2, 0.f), 1.f);
    ((float4*)boxes)[i] = make_float4(x1, y1, x2, y2);
}

__global__ __launch_bounds__(256) void decode_k(const float* __restrict__ loc,
                                                const float* __restrict__ anc,
                                                float* __restrict__ boxes) {
    int i = blockIdx.x * 256 + threadIdx.x;
    if (i < NB * NA) decode_body(i, loc, anc, boxes);
}

// ------- fused prep: decode (1 box/thread) + u8-code transpose slab (1:1 mapping) ----
#define TSLAB 256
__global__ __launch_bounds__(256) void prep_k(const float* __restrict__ conf,
                                              const float* __restrict__ loc,
                                              const float* __restrict__ anc,
                                              float* __restrict__ boxes,
                                              unsigned char* __restrict__ confT) {
    __shared__ unsigned char code[TSLAB * NC];     // 20736 B
    const int t = threadIdx.x;
    const int b = blockIdx.y, slab = blockIdx.x;
    // --- decode: thread t owns box (b, slab*256+t) — exp latency hides under loads ---
    decode_body(b * NA + slab * TSLAB + t, loc, anc, boxes);
    // --- transpose: conf f32 [B,A,C] -> confT8 u8 codes [B,C,A] ---
    const float4* src = (const float4*)(conf + ((size_t)b * NA + (size_t)slab * TSLAB) * NC);
    for (int i = t; i < (TSLAB * NC) / 4; i += 256) {
        float4 v = src[i];
        unsigned wrd = enc8(v.x) | (enc8(v.y) << 8) | (enc8(v.z) << 16) | (enc8(v.w) << 24);
        *(unsigned*)&code[4 * i] = wrd;            // contiguous 4 B/lane: conflict-free
    }
    __syncthreads();
    const int lane = t & 63, wv = t >> 6;
    for (int c = wv; c < NC; c += 4) {             // 64 lanes x 4 B = 256 B run per class
        unsigned v = 0u;
#pragma unroll
        for (int j = 0; j < 4; ++j)
            v |= (unsigned)code[(4 * lane + j) * NC + c] << (8 * j);
        *(unsigned*)(confT + ((size_t)b * NC + c) * NA + (size_t)slab * TSLAB + 4 * lane) = v;
    }
}

// ---- histogram/scatter over a 16-code word-quad (static indices; Q dies in-iter) ----
#define HIST16(Q)                                                          \
    do {                                                                   \
        unsigned wrds_[4] = {(Q).x, (Q).y, (Q).z, (Q).w};                  \
        _Pragma("unroll")                                                  \
        for (int m_ = 0; m_ < 4; ++m_) {                                   \
            _Pragma("unroll")                                              \
            for (int k_ = 0; k_ < 4; ++k_) {                               \
                unsigned bk_ = (wrds_[m_] >> (8 * k_)) & 0xFFu;            \
                if (bk_ != 0xFFu) atomicAdd(&s_hist[wv][bk_], 1u);         \
            }                                                              \
        }                                                                  \
    } while (0)

#define SCAT16(Q, BA)                                                      \
    do {                                                                   \
        unsigned wrds_[4] = {(Q).x, (Q).y, (Q).z, (Q).w};                  \
        _Pragma("unroll")                                                  \
        for (int m_ = 0; m_ < 4; ++m_) {                                   \
            _Pragma("unroll")                                              \
            for (int k_ = 0; k_ < 4; ++k_) {                               \
                int bk_ = (int)((wrds_[m_] >> (8 * k_)) & 0xFFu);          \
                if (bk_ >= trLo && bk_ < trHi)                             \
                    s_ix[atomicAdd(&s_cur[bk_], 1u)] =                     \
                        (unsigned short)((BA) + 4 * m_ + k_);              \
            }                                                              \
        }                                                                  \
    } while (0)

// ---- bucket-sorted lazy greedy NMS v14: R6 base + parallel-phase score hoist -------
__global__ __launch_bounds__(256, 8) void nmsB14_k(const unsigned char* __restrict__ confT,
                                                   const float* __restrict__ conf,
                                                   const float* __restrict__ boxes,
                                                   float* __restrict__ out) {
#pragma clang fp contract(off)
    const int blk = blockIdx.x;
    const int b = blk / NC, c = blk - b * NC;
    const int t = threadIdx.x;
    const int lane = t & 63, wv = t >> 6;

    __shared__ unsigned short s_ix[TRC];        // 2048 B
    __shared__ unsigned s_off[NBK + 1];         // bucket starts (desc score order)
    __shared__ unsigned s_hist[4][NBK + 2];     // per-wave privatized hist (padded)
    __shared__ unsigned s_cur[NBK];             // scatter cursors
    __shared__ unsigned s_wsum[4];              // per-wave scan totals
    __shared__ float4 s_abox[TOPK];             // accepted boxes (b128 broadcast reads)
    __shared__ float s_aarea[TOPK];             // accepted areas
    __shared__ float4 s_cbox[256];              // per-round candidate boxes
    __shared__ float s_cscore[256];             // per-round candidate scores (hoisted)
    __shared__ unsigned long long s_kill[4];
    __shared__ int s_ctrl[16];
    // ctrl: 0=nacc 1=tmp 2..5=chunk starts 6=chunk end 7=bptr 8=maxbucket
    //       9=bigE0 10=bigE1 11=mode 12=trLo 13=trHi

    const uint4* row16 = (const uint4*)(confT + ((size_t)b * NC + c) * NA); // 16 codes/16B
    const float* cp = conf + ((size_t)b * NA) * NC + c;   // exact scores, L3-hot
    const float4* bb = (const float4*)boxes + (size_t)b * NA;
    float* orow = out + ((size_t)b * NC + c) * (TOPK * 5);

    for (int i = t; i < 4 * (NBK + 2); i += 256) ((unsigned*)s_hist)[i] = 0u;
    if (t == 0) { s_ctrl[0] = 0; s_ctrl[8] = 0; s_ctrl[12] = 0; }
    __syncthreads();

    // --- global pass 1: histogram fused on the in-flight registers (q dies in-iter) ---
#pragma unroll
    for (int r = 0; r < 4; ++r) {
        uint4 q = row16[t + 256 * r];
        HIST16(q);
    }
    __syncthreads();

    // --- reduce 4 copies + maxbucket + wave-shuffle exclusive prefix (2 barriers) ---
    unsigned cnt = 0u;
    if (t < NBK) {
        cnt = s_hist[0][t] + s_hist[1][t] + s_hist[2][t] + s_hist[3][t];
        atomicMax(&s_ctrl[8], (int)cnt);
    }
    unsigned v = cnt;
#pragma unroll
    for (int off = 1; off < 64; off <<= 1) {
        unsigned o = __shfl_up(v, off);
        if (lane >= off) v += o;
    }
    if (lane == 63) s_wsum[wv] = v;
    __syncthreads();
    unsigned basep = 0u;
    for (int w2 = 0; w2 < wv; ++w2) basep += s_wsum[w2];
    v += basep;
    if (t < NBK) s_off[t + 1] = v;
    if (t == 0) s_off[0] = 0u;
    __syncthreads();

    if (s_ctrl[8] <= TRC) {
        // =========================== fast path: tranche loop ===========================
        while (true) {
            if (t == 0) {
                int lo = s_ctrl[12];
                int hi = lo;
                while (hi < NBK && s_off[hi + 1] - s_off[lo] <= (unsigned)TRC) hi++;
                s_ctrl[13] = hi;
            }
            __syncthreads();
            const int trLo = s_ctrl[12], trHi = s_ctrl[13];
            const unsigned tbase = s_off[trLo], tend = s_off[trHi];
            if (tbase == tend) break;               // no candidates remain
            for (int i = trLo + t; i < trHi; i += 256) s_cur[i] = s_off[i] - tbase;
            __syncthreads();
            // --- scatter tranche's anchor indices (code row is L2/L3-hot, 16 KB) ---
#pragma unroll
            for (int r = 0; r < 4; ++r) {
                uint4 q = row16[t + 256 * r];
                SCAT16(q, 16 * (t + 256 * r));
            }
            if (t == 0) s_ctrl[7] = trLo;
            __syncthreads();

            // --- rounds: 4 bucket-aligned chunks of <=64, parallel test + serial resolve ---
            while (true) {
                if (t == 0) {
                    int bp = s_ctrl[7];
                    int mode;
                    if (bp >= trHi || s_off[bp] >= tend) {
                        mode = 2;
                    } else {
                        unsigned pos = s_off[bp] - tbase;
                        int bpl = bp;
                        unsigned q = pos;
                        for (int w = 0; w < 4; ++w) {
                            s_ctrl[2 + w] = (int)q;
                            while (bpl < trHi && (s_off[bpl + 1] - tbase - q) <= 64u) bpl++;
                            q = (bpl < trHi) ? s_off[bpl] - tbase : tend - tbase;
                        }
                        s_ctrl[6] = (int)q;
                        s_ctrl[7] = bpl;
                        mode = 0;
                        if (q == pos) {            // first bucket > 64 entries (rare)
                            mode = 1;
                            s_ctrl[9] = (int)pos;
                            s_ctrl[10] = (int)(s_off[bp + 1] - tbase);
                            s_ctrl[7] = bp + 1;
                        }
                    }
                    s_ctrl[11] = mode;
                }
                __syncthreads();
                const int mode = s_ctrl[11];
                if (mode == 2) break;
                const int nacc0 = s_ctrl[0];

                if (mode == 0) {
                    const unsigned q0 = (unsigned)s_ctrl[2 + wv];
                    const unsigned q1 = (unsigned)s_ctrl[3 + wv];
                    const int mw = (int)(q1 - q0);
                    const bool valid = lane < mw;
                    int ii = (int)q0 + lane; if (ii > TRC - 1) ii = TRC - 1;
                    int a = valid ? (int)s_ix[ii] : 0;
                    float4 bxv = bb[a];
                    float sc = valid ? cp[(size_t)a * NC] : 0.f;   // hoisted: overlaps bb[a]
                    if (!valid) bxv = make_float4(0.f, 0.f, 0.f, 0.f);
                    s_cbox[wv * 64 + lane] = bxv;
                    s_cscore[wv * 64 + lane] = sc;
                    float mar = (bxv.z - bxv.x) * (bxv.w - bxv.y);
                    bool kill = !valid;
                    for (int j = 0; j < nacc0; ++j) {
                        float4 ab = s_abox[j];
                        float aa = s_aarea[j];
                        float xx1 = fmaxf(ab.x, bxv.x), yy1 = fmaxf(ab.y, bxv.y);
                        float xx2 = fminf(ab.z, bxv.z), yy2 = fminf(ab.w, bxv.w);
                        float iw = fmaxf(xx2 - xx1, 0.f), ih = fmaxf(yy2 - yy1, 0.f);
                        float inter = iw * ih;
                        float den = (aa + mar) - inter;
                        if (iou_gt_half(inter, den)) kill = true;
                        // amortized early-exit: one ballot per 8 accepted boxes
                        if ((j & 7) == 7 && __ballot(kill) == ~0ull) break;
                    }
                    unsigned long long km = __ballot(kill);
                    if (lane == 0) s_kill[wv] = km;
                    __syncthreads();

                    if (wv == 0) {
                        int na = nacc0;
                        for (int cc = 0; cc < 4 && na < TOPK; ++cc) {
                            const unsigned e0 = (unsigned)s_ctrl[2 + cc];
                            const unsigned e1 = (unsigned)s_ctrl[3 + cc];
                            const int mc = (int)(e1 - e0);
                            if (mc <= 0) continue;
                            unsigned long long alive = ~s_kill[cc];
                            if (mc < 64) alive &= (1ull << mc) - 1ull;
                            int jj = (int)e0 + lane; if (jj > TRC - 1) jj = TRC - 1;
                            int aj = (lane < mc) ? (int)s_ix[jj] : 0;
                            float myscore = s_cscore[cc * 64 + lane];  // LDS, no L3 wait
                            float4 mybx = s_cbox[cc * 64 + lane];
                            float mar2 = (mybx.z - mybx.x) * (mybx.w - mybx.y);
                            for (int j = nacc0; j < na && alive; ++j) {
                                float4 ab = s_abox[j];
                                float aa = s_aarea[j];
                                float xx1 = fmaxf(ab.x, mybx.x), yy1 = fmaxf(ab.y, mybx.y);
                                float xx2 = fminf(ab.z, mybx.z), yy2 = fminf(ab.w, mybx.w);
                                float iw = fmaxf(xx2 - xx1, 0.f), ih = fmaxf(yy2 - yy1, 0.f);
                                float inter = iw * ih;
                                float den = (aa + mar2) - inter;
                                bool sup = iou_gt_half(inter, den);
                                alive &= ~__ballot(sup);
                            }
                            unsigned long long mykey =
                                ((unsigned long long)__float_as_uint(myscore) << 32) |
                                (unsigned)(16383 - aj);
                            while (alive && na < TOPK) {
                                unsigned long long kk = ((alive >> lane) & 1ull) ? mykey : 0ull;
                                int src = lane;
                                for (int off = 32; off; off >>= 1) {
                                    unsigned long long ok = __shfl_xor(kk, off);
                                    int osrc = __shfl_xor(src, off);
                                    if (ok > kk) { kk = ok; src = osrc; }
                                }
                                float4 wb = s_cbox[cc * 64 + src];
                                float wscore = __shfl(myscore, src);
                                float war = (wb.z - wb.x) * (wb.w - wb.y);
                                if (lane == 0) {
                                    orow[na * 5 + 0] = wscore;
                                    orow[na * 5 + 1] = wb.x; orow[na * 5 + 2] = wb.y;
                                    orow[na * 5 + 3] = wb.z; orow[na * 5 + 4] = wb.w;
                                    s_abox[na] = wb;
                                    s_aarea[na] = war;
                                }
                                na++;
                                alive &= ~(1ull << src);
                                if (alive) {
                                    float xx1 = fmaxf(wb.x, mybx.x), yy1 = fmaxf(wb.y, mybx.y);
                                    float xx2 = fminf(wb.z, mybx.z), yy2 = fminf(wb.w, mybx.w);
                                    float iw = fmaxf(xx2 - xx1, 0.f), ih = fmaxf(yy2 - yy1, 0.f);
                                    float inter = iw * ih;
                                    float den = (war + mar2) - inter;
                                    bool sup = iou_gt_half(inter, den);
                                    alive &= ~__ballot(sup);
                                }
                            }
                        }
                        if (lane == 0) s_ctrl[0] = na;
                    }
                    __syncthreads();
                } else {
                    // big-bucket (>64 in one bucket, <=TRC): wave-0 extraction
                    const int e0 = s_ctrl[9], e1 = s_ctrl[10];
                    if (wv == 0) {
                        int na = s_ctrl[0];
                        while (na < TOPK) {
                            unsigned long long bk = 0ull; int bpos = 0;
                            for (int i = e0 + lane; i < e1; i += 64) {
                                int av = (int)s_ix[i];
                                if (av != 0xFFFF) {
                                    float vv = cp[(size_t)av * NC];
                                    unsigned long long k =
                                        ((unsigned long long)__float_as_uint(vv) << 32) |
                                        (unsigned)(16383 - av);
                                    if (k > bk) { bk = k; bpos = i; }
                                }
                            }
                            for (int off = 32; off; off >>= 1) {
                                unsigned long long ok = __shfl_xor(bk, off);
                                int op = __shfl_xor(bpos, off);
                                if (ok > bk) { bk = ok; bpos = op; }
                            }
                            if (bk == 0ull) break;
                            int a = (int)s_ix[bpos];
                            float wscore = __uint_as_float((unsigned)(bk >> 32));
                            if (lane == 0) s_ix[bpos] = 0xFFFFu;     // consume
                            float4 wb = bb[a];
                            float war = (wb.z - wb.x) * (wb.w - wb.y);
                            bool sup = false;
                            if (lane < na) {
                                float4 ab = s_abox[lane];
                                float aa = s_aarea[lane];
                                float xx1 = fmaxf(ab.x, wb.x), yy1 = fmaxf(ab.y, wb.y);
                                float xx2 = fminf(ab.z, wb.z), yy2 = fminf(ab.w, wb.w);
                                float iw = fmaxf(xx2 - xx1, 0.f), ih = fmaxf(yy2 - yy1, 0.f);
                                float inter = iw * ih;
                                float den = (aa + war) - inter;
                                sup = iou_gt_half(inter, den);
                            }
                            if (__ballot(sup) == 0ull) {
                                if (lane == 0) {
                                    orow[na * 5 + 0] = wscore;
                                    orow[na * 5 + 1] = wb.x; orow[na * 5 + 2] = wb.y;
                                    orow[na * 5 + 3] = wb.z; orow[na * 5 + 4] = wb.w;
                                    s_abox[na] = wb;
                                    s_aarea[na] = war;
                                }
                                na++;
                            }
                        }
                        if (lane == 0) s_ctrl[0] = na;
                    }
                    __syncthreads();
                }
                if (s_ctrl[0] >= TOPK) break;
            }
            // --- tranche done ---
            if (s_ctrl[0] >= TOPK || trHi >= NBK) break;
            if (t == 0) s_ctrl[12] = trHi;
            __syncthreads();
        }
    } else {
        // ===== exact windowed path (single bucket > TRC; P~0): strided conf scan =====
        float hi = 1.0f, delta = 0.02f;
        while (true) {
            if (s_ctrl[0] >= TOPK || hi <= 0.5f) break;
            float lo = fmaxf(hi - delta, 0.5f);
            if (t == 0) s_ctrl[1] = 0;
            __syncthreads();
            for (int a = t; a < NA; a += 256) {
                float vv = cp[(size_t)a * NC];
                if (vv > lo && vv <= hi) {
                    int p = atomicAdd(&s_ctrl[1], 1);
                    if (p < TRC) s_ix[p] = (unsigned short)a;
                }
            }
            __syncthreads();
            int m = s_ctrl[1];
            if (m > TRC) { delta *= 0.5f; continue; }
            if (wv == 0) {
                int na = s_ctrl[0];
                while (na < TOPK) {
                    unsigned long long bk = 0ull; int bpos = 0;
                    for (int i = lane; i < m; i += 64) {
                        int av = (int)s_ix[i];
                        if (av != 0xFFFF) {
                            float vv = cp[(size_t)av * NC];
                            unsigned long long k =
                                ((unsigned long long)__float_as_uint(vv) << 32) |
                                (unsigned)(16383 - av);
                            if (k > bk) { bk = k; bpos = i; }
                        }
                    }
                    for (int off = 32; off; off >>= 1) {
                        unsigned long long ok = __shfl_xor(bk, off);
                        int op = __shfl_xor(bpos, off);
                        if (ok > bk) { bk = ok; bpos = op; }
                    }
                    if (bk == 0ull) break;
                    int a = (int)s_ix[bpos];
                    float wscore = __uint_as_float((unsigned)(bk >> 32));
                    if (lane == 0) s_ix[bpos] = 0xFFFFu;
                    float4 wb = bb[a];
                    float war = (wb.z - wb.x) * (wb.w - wb.y);
                    bool sup = false;
                    if (lane < na) {
                        float4 ab = s_abox[lane];
                        float aa = s_aarea[lane];
                        float xx1 = fmaxf(ab.x, wb.x), yy1 = fmaxf(ab.y, wb.y);
                        float xx2 = fminf(ab.z, wb.z), yy2 = fminf(ab.w, wb.w);
                        float iw = fmaxf(xx2 - xx1, 0.f), ih = fmaxf(yy2 - yy1, 0.f);
                        float inter = iw * ih;
                        float den = (aa + war) - inter;
                        sup = iou_gt_half(inter, den);
                    }
                    if (__ballot(sup) == 0ull) {
                        if (lane == 0) {
                            orow[na * 5 + 0] = wscore;
                            orow[na * 5 + 1] = wb.x; orow[na * 5 + 2] = wb.y;
                            orow[na * 5 + 3] = wb.z; orow[na * 5 + 4] = wb.w;
                            s_abox[na] = wb;
                            s_aarea[na] = war;
                        }
                        na++;
                    }
                }
                if (lane == 0) s_ctrl[0] = na;
            }
            __syncthreads();
            hi = lo;
        }
    }

    __syncthreads();
    const int naF = s_ctrl[0];
    for (int z = naF * 5 + t; z < TOPK * 5; z += 256) orow[z] = 0.f;
}

// ============== round-1 fallback (only if ws too small for fast path) ==============
#define OTHREADS 1024
#define OCAP 10240
#define OJMAX 10

__global__ __launch_bounds__(OTHREADS) void nms_old_k(const float* __restrict__ conf,
                                                      const float* __restrict__ boxes,
                                                      float* __restrict__ out) {
#pragma clang fp contract(off)
    const int blk = blockIdx.x;
    const int b = blk / NC, c = blk - b * NC;
    const int t = threadIdx.x;
    const int lane = t & 63, wid = t >> 6;
    __shared__ float s_val[OCAP];
    __shared__ unsigned short s_idx[OCAP];
    __shared__ float s_ps[2][16];
    __shared__ int s_pa[2][16];
    __shared__ int s_n;
    if (t == 0) s_n = 0;
    __syncthreads();
    const float* cp = conf + ((size_t)b * NA) * NC + c;
    float v[NA / OTHREADS];
#pragma unroll
    for (int r = 0; r < NA / OTHREADS; ++r)
        v[r] = cp[(size_t)(r * OTHREADS + t) * NC];
#pragma unroll
    for (int r = 0; r < NA / OTHREADS; ++r) {
        int a = r * OTHREADS + t;
        bool alive = v[r] > 0.5f;
        unsigned long long m = __ballot(alive);
        int cnt = __popcll(m);
        int base = 0;
        if (lane == 0 && cnt) base = atomicAdd(&s_n, cnt);
        base = __shfl(base, 0);
        if (alive) {
            int p = base + __popcll(m & ((1ull << lane) - 1));
            if (p < OCAP) { s_val[p] = v[r]; s_idx[p] = (unsigned short)a; }
        }
    }
    __syncthreads();
    int n = s_n; if (n > OCAP) n = OCAP;
    const int jn = (n + OTHREADS - 1) / OTHREADS;
    const float4* bb = (const float4*)boxes + (size_t)b * NA;
    float sc[OJMAX]; float4 bx[OJMAX]; int ia[OJMAX];
#pragma unroll
    for (int j = 0; j < OJMAX; ++j) {
        sc[j] = NEGF; ia[j] = 0x7fffffff; bx[j] = make_float4(0.f, 0.f, 0.f, 0.f);
        int p = j * OTHREADS + t;
        if (p < n) { sc[j] = s_val[p]; ia[j] = (int)s_idx[p]; bx[j] = bb[ia[j]]; }
    }
    float* orow = out + (size_t)blk * (TOPK * 5);
    int k = 0;
    for (; k < TOPK; ++k) {
        float ms = NEGF; int ma = 0x7fffffff;
#pragma unroll
        for (int j = 0; j < OJMAX; ++j) {
            if (j < jn) {
                bool better = (sc[j] > ms) || (sc[j] == ms && ia[j] < ma);
                ms = better ? sc[j] : ms;
                ma = better ? ia[j] : ma;
            }
        }
#pragma unroll
        for (int off = 32; off; off >>= 1) {
            float os = __shfl_xor(ms, off);
            int oa = __shfl_xor(ma, off);
            if (os > ms || (os == ms && oa < ma)) { ms = os; ma = oa; }
        }
        int pb = k & 1;
        if (lane == 0) { s_ps[pb][wid] = ms; s_pa[pb][wid] = ma; }
        __syncthreads();
        float wsv = NEGF; int wa = 0x7fffffff;
#pragma unroll
        for (int w = 0; w < 16; ++w) {
            float os = s_ps[pb][w]; int oa = s_pa[pb][w];
            if (os > wsv || (os == wsv && oa < wa)) { wsv = os; wa = oa; }
        }
        if (!(wsv > NEGF)) break;
        float4 wb = bb[wa];
        float warea = (wb.z - wb.x) * (wb.w - wb.y);
        if (t == 0) {
            orow[k * 5 + 0] = wsv;
            orow[k * 5 + 1] = wb.x; orow[k * 5 + 2] = wb.y;
            orow[k * 5 + 3] = wb.z; orow[k * 5 + 4] = wb.w;
        }
#pragma unroll
        for (int j = 0; j < OJMAX; ++j) {
            if (j < jn) {
                float xx1 = fmaxf(wb.x, bx[j].x);
                float yy1 = fmaxf(wb.y, bx[j].y);
                float xx2 = fminf(wb.z, bx[j].z);
                float yy2 = fminf(wb.w, bx[j].w);
                float iw = fmaxf(xx2 - xx1, 0.f);
                float ih = fmaxf(yy2 - yy1, 0.f);
                float inter = iw * ih;
                float aj = (bx[j].z - bx[j].x) * (bx[j].w - bx[j].y);
                float denom = (warea + aj) - inter;
                bool supp = ((double)inter > (double)denom * SUPC) || (ia[j] == wa);
                if (supp) sc[j] = NEGF;
            }
        }
    }
    for (int z = k * 5 + t; z < TOPK * 5; z += OTHREADS) orow[z] = 0.f;
}

extern "C" void kernel_launch(void* const* d_in, const int* in_sizes, int n_in,
                              void* d_out, int out_size, void* d_ws, size_t ws_size,
                              hipStream_t stream) {
    const float* conf = (const float*)d_in[0];   // [B,A,C] f32
    const float* loc  = (const float*)d_in[1];   // [B,A,4] f32
    const float* anc  = (const float*)d_in[2];   // [A,4]   f32
    float* boxes = (float*)d_ws;

    if (ws_size >= WS_FULL) {
        unsigned char* confT = (unsigned char*)((char*)d_ws + WS_CONFT_OFF);
        dim3 tg(NA / TSLAB, NB);                 // fused decode+transpose, 1024 blocks
        prep_k<<<tg, 256, 0, stream>>>(conf, loc, anc, boxes, confT);
        nmsB14_k<<<NB * NC, 256, 0, stream>>>(confT, conf, boxes, (float*)d_out);
    } else {
        decode_k<<<(NB * NA + 255) / 256, 256, 0, stream>>>(loc, anc, boxes);
        nms_old_k<<<NB * NC, OTHREADS, 0, stream>>>(conf, boxes, (float*)d_out);
    }
}

// Round 9
// 190.730 us; speedup vs baseline: 1.0695x; 1.0303x over previous
//
#include <hip/hip_runtime.h>
#include <math.h>

#define NB 16
#define NA 16384
#define NC 81
#define TOPK 50
#define NBK 255                            // u8 buckets 0..254 (255=sentinel)
#define TRC 1024                           // lazy tranche capacity (R3-verified best)
#define NEGF (-__builtin_inff())
#define SUPC 0.5000000298023223876953125   // 0.5 + 2^-25 (exact in double)

typedef unsigned long long ull;

// ws layout: boxes [NB*NA*4 f32] @0 (4 MiB), confT8 [NB*NC*NA u8] @4 MiB (21.2 MB)
#define WS_CONFT_OFF  ((size_t)4194304)
#define WS_FULL  (WS_CONFT_OFF + (size_t)NB * NC * NA)       // 25,427,968

// exact f32 form of: round_f32(inter/den) > 0.5  (== inter > den*(0.5+2^-25))
__device__ __forceinline__ bool iou_gt_half(float inter, float den) {
    return fmaf(den, -0.5f, inter) > den * 0x1p-25f;
}

// score -> u8 code: 8-bit DESCENDING bucket for v in (0.5,1); 0xFF = not-candidate.
__device__ __forceinline__ unsigned enc8(float v) {
    unsigned e = 0xFFu;
    if (v > 0.5f) {
        unsigned d = 255u - ((__float_as_uint(v) >> 15) & 0xFFu);
        e = (d > 254u) ? 254u : d;
    }
    return e;
}

// ---------------- decode + clip (bit-verified rounds 1-8 — DO NOT TOUCH) ----------
__device__ __forceinline__ void decode_body(int i, const float* __restrict__ loc,
                                            const float* __restrict__ anc,
                                            float* __restrict__ boxes) {
#pragma clang fp contract(off)
    int a = i & (NA - 1);
    float4 an = ((const float4*)anc)[a];
    float4 ld = ((const float4*)loc)[i];
    float cx = an.x + (ld.x * 0.1f) * an.z;
    float cy = an.y + (ld.y * 0.1f) * an.w;
    float w = an.z * (float)exp((double)(ld.z * 0.2f));
    float h = an.w * (float)exp((double)(ld.w * 0.2f));
    float x1 = cx - w * 0.5f;
    float y1 = cy - h * 0.5f;
    float x2 = x1 + w;
    float y2 = y1 + h;
    x1 = fminf(fmaxf(x1, 0.f), 1.f);
    y1 = fminf(fmaxf(y1, 0.f), 1.f);
    x2 = fminf(fmaxf(x2, 0.f), 1.f);
    y2 = fminf(fmaxf(y2, 0.f), 1.f);
    ((float4*)boxes)[i] = make_float4(x1, y1, x2, y2);
}

__global__ __launch_bounds__(256) void decode_k(const float* __restrict__ loc,
                                                const float* __restrict__ anc,
                                                float* __restrict__ boxes) {
    int i = blockIdx.x * 256 + threadIdx.x;
    if (i < NB * NA) decode_body(i, loc, anc, boxes);
}

// ------- fused prep: decode (1 box/thread) + u8-code transpose slab (1:1 mapping) ----
#define TSLAB 256
__global__ __launch_bounds__(256) void prep_k(const float* __restrict__ conf,
                                              const float* __restrict__ loc,
                                              const float* __restrict__ anc,
                                              float* __restrict__ boxes,
                                              unsigned char* __restrict__ confT) {
    __shared__ unsigned char code[TSLAB * NC];     // 20736 B
    const int t = threadIdx.x;
    const int b = blockIdx.y, slab = blockIdx.x;
    // --- decode: thread t owns box (b, slab*256+t) — exp latency hides under loads ---
    decode_body(b * NA + slab * TSLAB + t, loc, anc, boxes);
    // --- transpose: conf f32 [B,A,C] -> confT8 u8 codes [B,C,A] ---
    const float4* src = (const float4*)(conf + ((size_t)b * NA + (size_t)slab * TSLAB) * NC);
    for (int i = t; i < (TSLAB * NC) / 4; i += 256) {
        float4 v = src[i];
        unsigned wrd = enc8(v.x) | (enc8(v.y) << 8) | (enc8(v.z) << 16) | (enc8(v.w) << 24);
        *(unsigned*)&code[4 * i] = wrd;            // contiguous 4 B/lane: conflict-free
    }
    __syncthreads();
    const int lane = t & 63, wv = t >> 6;
    for (int c = wv; c < NC; c += 4) {             // 64 lanes x 4 B = 256 B run per class
        unsigned v = 0u;
#pragma unroll
    for (int j = 0; j < 4; ++j)
            v |= (unsigned)code[(4 * lane + j) * NC + c] << (8 * j);
        *(unsigned*)(confT + ((size_t)b * NC + c) * NA + (size_t)slab * TSLAB + 4 * lane) = v;
    }
}

// ---- histogram/scatter over a 16-code word-quad (static indices; Q dies in-iter) ----
#define HIST16(Q)                                                          \
    do {                                                                   \
        unsigned wrds_[4] = {(Q).x, (Q).y, (Q).z, (Q).w};                  \
        _Pragma("unroll")                                                  \
        for (int m_ = 0; m_ < 4; ++m_) {                                   \
            _Pragma("unroll")                                              \
            for (int k_ = 0; k_ < 4; ++k_) {                               \
                unsigned bk_ = (wrds_[m_] >> (8 * k_)) & 0xFFu;            \
                if (bk_ != 0xFFu) atomicAdd(&s_hist[wv][bk_], 1u);         \
            }                                                              \
        }                                                                  \
    } while (0)

#define SCAT16(Q, BA)                                                      \
    do {                                                                   \
        unsigned wrds_[4] = {(Q).x, (Q).y, (Q).z, (Q).w};                  \
        _Pragma("unroll")                                                  \
        for (int m_ = 0; m_ < 4; ++m_) {                                   \
            _Pragma("unroll")                                              \
            for (int k_ = 0; k_ < 4; ++k_) {                               \
                int bk_ = (int)((wrds_[m_] >> (8 * k_)) & 0xFFu);          \
                if (bk_ >= trLo && bk_ < trHi)                             \
                    s_ix[atomicAdd(&s_cur[bk_], 1u)] =                     \
                        (unsigned short)((BA) + 4 * m_ + k_);              \
            }                                                              \
        }                                                                  \
    } while (0)

// ---- bucket-sorted lazy greedy NMS v15: R6 base + bijective XCD swizzle (T1) -------
// 1296 blocks = 8 XCDs x 162; swizzle makes each XCD own exactly 2 batches, so its
// 4 MiB L2 holds those batches' boxes (2x256KB) + confT rows — scattered gathers
// in test/resolve become L2 hits instead of L3/HBM.
__global__ __launch_bounds__(256, 8) void nmsB15_k(const unsigned char* __restrict__ confT,
                                                   const float* __restrict__ conf,
                                                   const float* __restrict__ boxes,
                                                   float* __restrict__ out) {
#pragma clang fp contract(off)
    const int bid = blockIdx.x;
    const int blk = (bid & 7) * ((NB * NC) / 8) + (bid >> 3);   // bijective: 1296 = 8*162
    const int b = blk / NC, c = blk - b * NC;
    const int t = threadIdx.x;
    const int lane = t & 63, wv = t >> 6;

    __shared__ unsigned short s_ix[TRC];        // 2048 B
    __shared__ unsigned s_off[NBK + 1];         // bucket starts (desc score order)
    __shared__ unsigned s_hist[4][NBK + 2];     // per-wave privatized hist (padded)
    __shared__ unsigned s_cur[NBK];             // scatter cursors
    __shared__ unsigned s_wsum[4];              // per-wave scan totals
    __shared__ float4 s_abox[TOPK];             // accepted boxes (b128 broadcast reads)
    __shared__ float s_aarea[TOPK];             // accepted areas
    __shared__ float4 s_cbox[256];              // per-round candidate boxes
    __shared__ unsigned long long s_kill[4];
    __shared__ int s_ctrl[16];
    // ctrl: 0=nacc 1=tmp 2..5=chunk starts 6=chunk end 7=bptr 8=maxbucket
    //       9=bigE0 10=bigE1 11=mode 12=trLo 13=trHi

    const uint4* row16 = (const uint4*)(confT + ((size_t)b * NC + c) * NA); // 16 codes/16B
    const float* cp = conf + ((size_t)b * NA) * NC + c;   // exact scores, L2-hot
    const float4* bb = (const float4*)boxes + (size_t)b * NA;
    float* orow = out + ((size_t)b * NC + c) * (TOPK * 5);

    for (int i = t; i < 4 * (NBK + 2); i += 256) ((unsigned*)s_hist)[i] = 0u;
    if (t == 0) { s_ctrl[0] = 0; s_ctrl[8] = 0; s_ctrl[12] = 0; }
    __syncthreads();

    // --- global pass 1: histogram fused on the in-flight registers (q dies in-iter) ---
#pragma unroll
    for (int r = 0; r < 4; ++r) {
        uint4 q = row16[t + 256 * r];
        HIST16(q);
    }
    __syncthreads();

    // --- reduce 4 copies + maxbucket + wave-shuffle exclusive prefix (2 barriers) ---
    unsigned cnt = 0u;
    if (t < NBK) {
        cnt = s_hist[0][t] + s_hist[1][t] + s_hist[2][t] + s_hist[3][t];
        atomicMax(&s_ctrl[8], (int)cnt);
    }
    unsigned v = cnt;
#pragma unroll
    for (int off = 1; off < 64; off <<= 1) {
        unsigned o = __shfl_up(v, off);
        if (lane >= off) v += o;
    }
    if (lane == 63) s_wsum[wv] = v;
    __syncthreads();
    unsigned basep = 0u;
    for (int w2 = 0; w2 < wv; ++w2) basep += s_wsum[w2];
    v += basep;
    if (t < NBK) s_off[t + 1] = v;
    if (t == 0) s_off[0] = 0u;
    __syncthreads();

    if (s_ctrl[8] <= TRC) {
        // =========================== fast path: tranche loop ===========================
        while (true) {
            if (t == 0) {
                int lo = s_ctrl[12];
                int hi = lo;
                while (hi < NBK && s_off[hi + 1] - s_off[lo] <= (unsigned)TRC) hi++;
                s_ctrl[13] = hi;
            }
            __syncthreads();
            const int trLo = s_ctrl[12], trHi = s_ctrl[13];
            const unsigned tbase = s_off[trLo], tend = s_off[trHi];
            if (tbase == tend) break;               // no candidates remain
            for (int i = trLo + t; i < trHi; i += 256) s_cur[i] = s_off[i] - tbase;
            __syncthreads();
            // --- scatter tranche's anchor indices (code row is L2/L3-hot, 16 KB) ---
#pragma unroll
            for (int r = 0; r < 4; ++r) {
                uint4 q = row16[t + 256 * r];
                SCAT16(q, 16 * (t + 256 * r));
            }
            if (t == 0) s_ctrl[7] = trLo;
            __syncthreads();

            // --- rounds: 4 bucket-aligned chunks of <=64, parallel test + serial resolve ---
            while (true) {
                if (t == 0) {
                    int bp = s_ctrl[7];
                    int mode;
                    if (bp >= trHi || s_off[bp] >= tend) {
                        mode = 2;
                    } else {
                        unsigned pos = s_off[bp] - tbase;
                        int bpl = bp;
                        unsigned q = pos;
                        for (int w = 0; w < 4; ++w) {
                            s_ctrl[2 + w] = (int)q;
                            while (bpl < trHi && (s_off[bpl + 1] - tbase - q) <= 64u) bpl++;
                            q = (bpl < trHi) ? s_off[bpl] - tbase : tend - tbase;
                        }
                        s_ctrl[6] = (int)q;
                        s_ctrl[7] = bpl;
                        mode = 0;
                        if (q == pos) {            // first bucket > 64 entries (rare)
                            mode = 1;
                            s_ctrl[9] = (int)pos;
                            s_ctrl[10] = (int)(s_off[bp + 1] - tbase);
                            s_ctrl[7] = bp + 1;
                        }
                    }
                    s_ctrl[11] = mode;
                }
                __syncthreads();
                const int mode = s_ctrl[11];
                if (mode == 2) break;
                const int nacc0 = s_ctrl[0];

                if (mode == 0) {
                    const unsigned q0 = (unsigned)s_ctrl[2 + wv];
                    const unsigned q1 = (unsigned)s_ctrl[3 + wv];
                    const int mw = (int)(q1 - q0);
                    const bool valid = lane < mw;
                    int ii = (int)q0 + lane; if (ii > TRC - 1) ii = TRC - 1;
                    int a = valid ? (int)s_ix[ii] : 0;
                    float4 bxv = bb[a];
                    if (!valid) bxv = make_float4(0.f, 0.f, 0.f, 0.f);
                    s_cbox[wv * 64 + lane] = bxv;
                    float mar = (bxv.z - bxv.x) * (bxv.w - bxv.y);
                    bool kill = !valid;
                    for (int j = 0; j < nacc0; ++j) {
                        float4 ab = s_abox[j];
                        float aa = s_aarea[j];
                        float xx1 = fmaxf(ab.x, bxv.x), yy1 = fmaxf(ab.y, bxv.y);
                        float xx2 = fminf(ab.z, bxv.z), yy2 = fminf(ab.w, bxv.w);
                        float iw = fmaxf(xx2 - xx1, 0.f), ih = fmaxf(yy2 - yy1, 0.f);
                        float inter = iw * ih;
                        float den = (aa + mar) - inter;
                        if (iou_gt_half(inter, den)) kill = true;
                        // amortized early-exit: one ballot per 8 accepted boxes
                        if ((j & 7) == 7 && __ballot(kill) == ~0ull) break;
                    }
                    unsigned long long km = __ballot(kill);
                    if (lane == 0) s_kill[wv] = km;
                    __syncthreads();

                    if (wv == 0) {
                        int na = nacc0;
                        for (int cc = 0; cc < 4 && na < TOPK; ++cc) {
                            const unsigned e0 = (unsigned)s_ctrl[2 + cc];
                            const unsigned e1 = (unsigned)s_ctrl[3 + cc];
                            const int mc = (int)(e1 - e0);
                            if (mc <= 0) continue;
                            unsigned long long alive = ~s_kill[cc];
                            if (mc < 64) alive &= (1ull << mc) - 1ull;
                            int jj = (int)e0 + lane; if (jj > TRC - 1) jj = TRC - 1;
                            int aj = (lane < mc) ? (int)s_ix[jj] : 0;
                            float myscore = cp[(size_t)aj * NC];       // exact f32, L2-hot
                            float4 mybx = s_cbox[cc * 64 + lane];
                            float mar2 = (mybx.z - mybx.x) * (mybx.w - mybx.y);
                            for (int j = nacc0; j < na && alive; ++j) {
                                float4 ab = s_abox[j];
                                float aa = s_aarea[j];
                                float xx1 = fmaxf(ab.x, mybx.x), yy1 = fmaxf(ab.y, mybx.y);
                                float xx2 = fminf(ab.z, mybx.z), yy2 = fminf(ab.w, mybx.w);
                                float iw = fmaxf(xx2 - xx1, 0.f), ih = fmaxf(yy2 - yy1, 0.f);
                                float inter = iw * ih;
                                float den = (aa + mar2) - inter;
                                bool sup = iou_gt_half(inter, den);
                                alive &= ~__ballot(sup);
                            }
                            unsigned long long mykey =
                                ((unsigned long long)__float_as_uint(myscore) << 32) |
                                (unsigned)(16383 - aj);
                            while (alive && na < TOPK) {
                                unsigned long long kk = ((alive >> lane) & 1ull) ? mykey : 0ull;
                                int src = lane;
                                for (int off = 32; off; off >>= 1) {
                                    unsigned long long ok = __shfl_xor(kk, off);
                                    int osrc = __shfl_xor(src, off);
                                    if (ok > kk) { kk = ok; src = osrc; }
                                }
                                float4 wb = s_cbox[cc * 64 + src];
                                float wscore = __shfl(myscore, src);
                                float war = (wb.z - wb.x) * (wb.w - wb.y);
                                if (lane == 0) {
                                    orow[na * 5 + 0] = wscore;
                                    orow[na * 5 + 1] = wb.x; orow[na * 5 + 2] = wb.y;
                                    orow[na * 5 + 3] = wb.z; orow[na * 5 + 4] = wb.w;
                                    s_abox[na] = wb;
                                    s_aarea[na] = war;
                                }
                                na++;
                                alive &= ~(1ull << src);
                                if (alive) {
                                    float xx1 = fmaxf(wb.x, mybx.x), yy1 = fmaxf(wb.y, mybx.y);
                                    float xx2 = fminf(wb.z, mybx.z), yy2 = fminf(wb.w, mybx.w);
                                    float iw = fmaxf(xx2 - xx1, 0.f), ih = fmaxf(yy2 - yy1, 0.f);
                                    float inter = iw * ih;
                                    float den = (war + mar2) - inter;
                                    bool sup = iou_gt_half(inter, den);
                                    alive &= ~__ballot(sup);
                                }
                            }
                        }
                        if (lane == 0) s_ctrl[0] = na;
                    }
                    __syncthreads();
                } else {
                    // big-bucket (>64 in one bucket, <=TRC): wave-0 extraction
                    const int e0 = s_ctrl[9], e1 = s_ctrl[10];
                    if (wv == 0) {
                        int na = s_ctrl[0];
                        while (na < TOPK) {
                            unsigned long long bk = 0ull; int bpos = 0;
                            for (int i = e0 + lane; i < e1; i += 64) {
                                int av = (int)s_ix[i];
                                if (av != 0xFFFF) {
                                    float vv = cp[(size_t)av * NC];
                                    unsigned long long k =
                                        ((unsigned long long)__float_as_uint(vv) << 32) |
                                        (unsigned)(16383 - av);
                                    if (k > bk) { bk = k; bpos = i; }
                                }
                            }
                            for (int off = 32; off; off >>= 1) {
                                unsigned long long ok = __shfl_xor(bk, off);
                                int op = __shfl_xor(bpos, off);
                                if (ok > bk) { bk = ok; bpos = op; }
                            }
                            if (bk == 0ull) break;
                            int a = (int)s_ix[bpos];
                            float wscore = __uint_as_float((unsigned)(bk >> 32));
                            if (lane == 0) s_ix[bpos] = 0xFFFFu;     // consume
                            float4 wb = bb[a];
                            float war = (wb.z - wb.x) * (wb.w - wb.y);
                            bool sup = false;
                            if (lane < na) {
                                float4 ab = s_abox[lane];
                                float aa = s_aarea[lane];
                                float xx1 = fmaxf(ab.x, wb.x), yy1 = fmaxf(ab.y, wb.y);
                                float xx2 = fminf(ab.z, wb.z), yy2 = fminf(ab.w, wb.w);
                                float iw = fmaxf(xx2 - xx1, 0.f), ih = fmaxf(yy2 - yy1, 0.f);
                                float inter = iw * ih;
                                float den = (aa + war) - inter;
                                sup = iou_gt_half(inter, den);
                            }
                            if (__ballot(sup) == 0ull) {
                                if (lane == 0) {
                                    orow[na * 5 + 0] = wscore;
                                    orow[na * 5 + 1] = wb.x; orow[na * 5 + 2] = wb.y;
                                    orow[na * 5 + 3] = wb.z; orow[na * 5 + 4] = wb.w;
                                    s_abox[na] = wb;
                                    s_aarea[na] = war;
                                }
                                na++;
                            }
                        }
                        if (lane == 0) s_ctrl[0] = na;
                    }
                    __syncthreads();
                }
                if (s_ctrl[0] >= TOPK) break;
            }
            // --- tranche done ---
            if (s_ctrl[0] >= TOPK || trHi >= NBK) break;
            if (t == 0) s_ctrl[12] = trHi;
            __syncthreads();
        }
    } else {
        // ===== exact windowed path (single bucket > TRC; P~0): strided conf scan =====
        float hi = 1.0f, delta = 0.02f;
        while (true) {
            if (s_ctrl[0] >= TOPK || hi <= 0.5f) break;
            float lo = fmaxf(hi - delta, 0.5f);
            if (t == 0) s_ctrl[1] = 0;
            __syncthreads();
            for (int a = t; a < NA; a += 256) {
                float vv = cp[(size_t)a * NC];
                if (vv > lo && vv <= hi) {
                    int p = atomicAdd(&s_ctrl[1], 1);
                    if (p < TRC) s_ix[p] = (unsigned short)a;
                }
            }
            __syncthreads();
            int m = s_ctrl[1];
            if (m > TRC) { delta *= 0.5f; continue; }
            if (wv == 0) {
                int na = s_ctrl[0];
                while (na < TOPK) {
                    unsigned long long bk = 0ull; int bpos = 0;
                    for (int i = lane; i < m; i += 64) {
                        int av = (int)s_ix[i];
                        if (av != 0xFFFF) {
                            float vv = cp[(size_t)av * NC];
                            unsigned long long k =
                                ((unsigned long long)__float_as_uint(vv) << 32) |
                                (unsigned)(16383 - av);
                            if (k > bk) { bk = k; bpos = i; }
                        }
                    }
                    for (int off = 32; off; off >>= 1) {
                        unsigned long long ok = __shfl_xor(bk, off);
                        int op = __shfl_xor(bpos, off);
                        if (ok > bk) { bk = ok; bpos = op; }
                    }
                    if (bk == 0ull) break;
                    int a = (int)s_ix[bpos];
                    float wscore = __uint_as_float((unsigned)(bk >> 32));
                    if (lane == 0) s_ix[bpos] = 0xFFFFu;
                    float4 wb = bb[a];
                    float war = (wb.z - wb.x) * (wb.w - wb.y);
                    bool sup = false;
                    if (lane < na) {
                        float4 ab = s_abox[lane];
                        float aa = s_aarea[lane];
                        float xx1 = fmaxf(ab.x, wb.x), yy1 = fmaxf(ab.y, wb.y);
                        float xx2 = fminf(ab.z, wb.z), yy2 = fminf(ab.w, wb.w);
                        float iw = fmaxf(xx2 - xx1, 0.f), ih = fmaxf(yy2 - yy1, 0.f);
                        float inter = iw * ih;
                        float den = (aa + war) - inter;
                        sup = iou_gt_half(inter, den);
                    }
                    if (__ballot(sup) == 0ull) {
                        if (lane == 0) {
                            orow[na * 5 + 0] = wscore;
                            orow[na * 5 + 1] = wb.x; orow[na * 5 + 2] = wb.y;
                            orow[na * 5 + 3] = wb.z; orow[na * 5 + 4] = wb.w;
                            s_abox[na] = wb;
                            s_aarea[na] = war;
                        }
                        na++;
                    }
                }
                if (lane == 0) s_ctrl[0] = na;
            }
            __syncthreads();
            hi = lo;
        }
    }

    __syncthreads();
    const int naF = s_ctrl[0];
    for (int z = naF * 5 + t; z < TOPK * 5; z += 256) orow[z] = 0.f;
}

// ============== round-1 fallback (only if ws too small for fast path) ==============
#define OTHREADS 1024
#define OCAP 10240
#define OJMAX 10

__global__ __launch_bounds__(OTHREADS) void nms_old_k(const float* __restrict__ conf,
                                                      const float* __restrict__ boxes,
                                                      float* __restrict__ out) {
#pragma clang fp contract(off)
    const int blk = blockIdx.x;
    const int b = blk / NC, c = blk - b * NC;
    const int t = threadIdx.x;
    const int lane = t & 63, wid = t >> 6;
    __shared__ float s_val[OCAP];
    __shared__ unsigned short s_idx[OCAP];
    __shared__ float s_ps[2][16];
    __shared__ int s_pa[2][16];
    __shared__ int s_n;
    if (t == 0) s_n = 0;
    __syncthreads();
    const float* cp = conf + ((size_t)b * NA) * NC + c;
    float v[NA / OTHREADS];
#pragma unroll
    for (int r = 0; r < NA / OTHREADS; ++r)
        v[r] = cp[(size_t)(r * OTHREADS + t) * NC];
#pragma unroll
    for (int r = 0; r < NA / OTHREADS; ++r) {
        int a = r * OTHREADS + t;
        bool alive = v[r] > 0.5f;
        unsigned long long m = __ballot(alive);
        int cnt = __popcll(m);
        int base = 0;
        if (lane == 0 && cnt) base = atomicAdd(&s_n, cnt);
        base = __shfl(base, 0);
        if (alive) {
            int p = base + __popcll(m & ((1ull << lane) - 1));
            if (p < OCAP) { s_val[p] = v[r]; s_idx[p] = (unsigned short)a; }
        }
    }
    __syncthreads();
    int n = s_n; if (n > OCAP) n = OCAP;
    const int jn = (n + OTHREADS - 1) / OTHREADS;
    const float4* bb = (const float4*)boxes + (size_t)b * NA;
    float sc[OJMAX]; float4 bx[OJMAX]; int ia[OJMAX];
#pragma unroll
    for (int j = 0; j < OJMAX; ++j) {
        sc[j] = NEGF; ia[j] = 0x7fffffff; bx[j] = make_float4(0.f, 0.f, 0.f, 0.f);
        int p = j * OTHREADS + t;
        if (p < n) { sc[j] = s_val[p]; ia[j] = (int)s_idx[p]; bx[j] = bb[ia[j]]; }
    }
    float* orow = out + (size_t)blk * (TOPK * 5);
    int k = 0;
    for (; k < TOPK; ++k) {
        float ms = NEGF; int ma = 0x7fffffff;
#pragma unroll
        for (int j = 0; j < OJMAX; ++j) {
            if (j < jn) {
                bool better = (sc[j] > ms) || (sc[j] == ms && ia[j] < ma);
                ms = better ? sc[j] : ms;
                ma = better ? ia[j] : ma;
            }
        }
#pragma unroll
        for (int off = 32; off; off >>= 1) {
            float os = __shfl_xor(ms, off);
            int oa = __shfl_xor(ma, off);
            if (os > ms || (os == ms && oa < ma)) { ms = os; ma = oa; }
        }
        int pb = k & 1;
        if (lane == 0) { s_ps[pb][wid] = ms; s_pa[pb][wid] = ma; }
        __syncthreads();
        float wsv = NEGF; int wa = 0x7fffffff;
#pragma unroll
        for (int w = 0; w < 16; ++w) {
            float os = s_ps[pb][w]; int oa = s_pa[pb][w];
            if (os > wsv || (os == wsv && oa < wa)) { wsv = os; wa = oa; }
        }
        if (!(wsv > NEGF)) break;
        float4 wb = bb[wa];
        float warea = (wb.z - wb.x) * (wb.w - wb.y);
        if (t == 0) {
            orow[k * 5 + 0] = wsv;
            orow[k * 5 + 1] = wb.x; orow[k * 5 + 2] = wb.y;
            orow[k * 5 + 3] = wb.z; orow[k * 5 + 4] = wb.w;
        }
#pragma unroll
        for (int j = 0; j < OJMAX; ++j) {
            if (j < jn) {
                float xx1 = fmaxf(wb.x, bx[j].x);
                float yy1 = fmaxf(wb.y, bx[j].y);
                float xx2 = fminf(wb.z, bx[j].z);
                float yy2 = fminf(wb.w, bx[j].w);
                float iw = fmaxf(xx2 - xx1, 0.f);
                float ih = fmaxf(yy2 - yy1, 0.f);
                float inter = iw * ih;
                float aj = (bx[j].z - bx[j].x) * (bx[j].w - bx[j].y);
                float denom = (warea + aj) - inter;
                bool supp = ((double)inter > (double)denom * SUPC) || (ia[j] == wa);
                if (supp) sc[j] = NEGF;
            }
        }
    }
    for (int z = k * 5 + t; z < TOPK * 5; z += OTHREADS) orow[z] = 0.f;
}

extern "C" void kernel_launch(void* const* d_in, const int* in_sizes, int n_in,
                              void* d_out, int out_size, void* d_ws, size_t ws_size,
                              hipStream_t stream) {
    const float* conf = (const float*)d_in[0];   // [B,A,C] f32
    const float* loc  = (const float*)d_in[1];   // [B,A,4] f32
    const float* anc  = (const float*)d_in[2];   // [A,4]   f32
    float* boxes = (float*)d_ws;

    if (ws_size >= WS_FULL) {
        unsigned char* confT = (unsigned char*)((char*)d_ws + WS_CONFT_OFF);
        dim3 tg(NA / TSLAB, NB);                 // fused decode+transpose, 1024 blocks
        prep_k<<<tg, 256, 0, stream>>>(conf, loc, anc, boxes, confT);
        nmsB15_k<<<NB * NC, 256, 0, stream>>>(confT, conf, boxes, (float*)d_out);
    } else {
        decode_k<<<(NB * NA + 255) / 256, 256, 0, stream>>>(loc, anc, boxes);
        nms_old_k<<<NB * NC, OTHREADS, 0, stream>>>(conf, boxes, (float*)d_out);
    }
}